// Round 8
// baseline (75.669 us; speedup 1.0000x reference)
//
#include <hip/hip_runtime.h>

#define T_ 500
#define R_ 50
#define NS_ 1000
#define H1_ 32
#define H2_ 16
#define NEG_ 0.2f
#define NROWS_ (NS_ * R_)   // 50000
#define RSTRIDE_ 8192       // 2048 blocks * 4 waves

__device__ __forceinline__ float lrelu(float x) { return x >= 0.f ? x : NEG_ * x; }

// One block per t: y1[t][c] = sum_f x[t][f] * gc1_w[f][c],  x=[state(2)|payoff row(500)|noise(2)]
__global__ __launch_bounds__(256) void k1_xw(const float* __restrict__ state,
                                             const float* __restrict__ payoff,
                                             const float* __restrict__ noise,
                                             const float* __restrict__ w,
                                             float* __restrict__ y1) {
    __shared__ float xs[504];
    __shared__ float red[8][H1_];
    int t = blockIdx.x, tid = threadIdx.x;
    for (int u = tid; u < T_; u += 256) xs[2 + u] = payoff[t * T_ + u];
    if (tid == 0) {
        xs[0] = state[t * 2];     xs[1] = state[t * 2 + 1];
        xs[502] = noise[t * 2];   xs[503] = noise[t * 2 + 1];
    }
    __syncthreads();
    int c = tid & 31, kg = tid >> 5;   // 8 k-groups x 32 channels
    float acc = 0.f;
#pragma unroll 7
    for (int f = kg; f < 504; f += 8) acc += xs[f] * w[f * H1_ + c];
    red[kg][c] = acc;
    __syncthreads();
    if (tid < H1_) {
        float a = 0.f;
#pragma unroll
        for (int s = 0; s < 8; ++s) a += red[s][tid];
        y1[t * H1_ + tid] = a;
    }
}

// One block per t: h1row = lrelu(bn(adj[t]@y1 + b)); y2[t][c2] = h1row @ g2w
__global__ __launch_bounds__(256) void k2_adj_fused(const float* __restrict__ adj,
                                                    const float* __restrict__ y1,
                                                    const float* __restrict__ b,
                                                    const float* __restrict__ gamma,
                                                    const float* __restrict__ beta,
                                                    const float* __restrict__ w2,
                                                    float* __restrict__ y2) {
    __shared__ float arow[T_];
    __shared__ float red[8][H1_];
    __shared__ float h1row[H1_];
    int t = blockIdx.x, tid = threadIdx.x;
    for (int u = tid; u < T_; u += 256) arow[u] = adj[t * T_ + u];
    __syncthreads();
    int c = tid & 31, kg = tid >> 5;
    float acc = 0.f;
#pragma unroll 4
    for (int u = kg; u < T_; u += 8) acc += arow[u] * y1[u * H1_ + c];
    red[kg][c] = acc;
    __syncthreads();
    if (tid < H1_) {
        float a = 0.f;
#pragma unroll
        for (int s = 0; s < 8; ++s) a += red[s][tid];
        h1row[tid] = lrelu((a + b[tid]) * gamma[t] + beta[t]);
    }
    __syncthreads();
    if (tid < H2_) {
        float a = 0.f;
#pragma unroll
        for (int cc = 0; cc < H1_; ++cc) a += h1row[cc] * w2[cc * H2_ + tid];
        y2[t * H2_ + tid] = a;
    }
}

// One block per t: xfrow = lrelu(bn(adj[t]@y2 + b2)); part1[t][j] = xfrow @ aw[t*16..t*16+16)
__global__ __launch_bounds__(256) void k3_adj2_aw(const float* __restrict__ adj,
                                                  const float* __restrict__ y2,
                                                  const float* __restrict__ b2,
                                                  const float* __restrict__ gamma,
                                                  const float* __restrict__ beta,
                                                  const float* __restrict__ aw,
                                                  float* __restrict__ part1) {
    __shared__ float arow[T_];
    __shared__ float red[16][H2_];
    __shared__ float xfr[H2_];
    int t = blockIdx.x, tid = threadIdx.x;
    for (int u = tid; u < T_; u += 256) arow[u] = adj[t * T_ + u];
    __syncthreads();
    int c2 = tid & 15, kg = tid >> 4;  // 16 k-groups x 16 channels
    float acc = 0.f;
#pragma unroll 4
    for (int u = kg; u < T_; u += 16) acc += arow[u] * y2[u * H2_ + c2];
    red[kg][c2] = acc;
    __syncthreads();
    if (tid < H2_) {
        float a = 0.f;
#pragma unroll
        for (int s = 0; s < 16; ++s) a += red[s][tid];
        xfr[tid] = lrelu((a + b2[tid]) * gamma[t] + beta[t]);
    }
    __syncthreads();
    float acc0 = 0.f, acc1 = 0.f;
#pragma unroll
    for (int c = 0; c < H2_; ++c) {
        float xv = xfr[c];
        const float* awr = aw + (t * H2_ + c) * T_;
        acc0 += xv * awr[tid];
        if (tid < T_ - 256) acc1 += xv * awr[256 + tid];
    }
    part1[t * T_ + tid] = acc0;
    if (tid < T_ - 256) part1[t * T_ + 256 + tid] = acc1;
}

// Block (r, y=q*2+jb): partial logits over t-quarter q, j-half jb.
// part2[q][r*T+j] = sum_{t in q} dloc[r][t]*av[t][j] + part1[t][j]
__global__ __launch_bounds__(256) void k4_logits_part(const float* __restrict__ dloc,
                                                      const float* __restrict__ av,
                                                      const float* __restrict__ part1,
                                                      float* __restrict__ part2) {
    int r = blockIdx.x;
    int jb = blockIdx.y & 1, q = blockIdx.y >> 1;
    __shared__ float drow[125];
    int tid = threadIdx.x;
    int t0 = q * 125;
    if (tid < 125) drow[tid] = dloc[r * T_ + t0 + tid];
    __syncthreads();
    if (tid >= 250) return;
    int j = jb * 250 + tid;
    float acc = 0.f;
#pragma unroll 5
    for (int i = 0; i < 125; ++i) {
        int t = t0 + i;
        acc += drow[i] * av[t * T_ + j] + part1[t * T_ + j];
    }
    part2[q * (R_ * T_) + r * T_ + j] = acc;
}

// elog[x] = exp(sum_q part2[q][x])   (exp folded here; row softmax later divides it out)
__global__ __launch_bounds__(256) void k4_reduce_exp(const float* __restrict__ part2,
                                                     float* __restrict__ elog) {
    int gid = blockIdx.x * 256 + threadIdx.x;
    if (gid >= R_ * T_) return;
    float v = part2[gid] + part2[R_ * T_ + gid] +
              part2[2 * R_ * T_ + gid] + part2[3 * R_ * T_ + gid];
    elog[gid] = __expf(v);
}

// Persistent grid, register-rotated software pipeline:
// gu prefetched depth-2 (HBM latency), elog depth-1 (L2). Compute of row i uses
// loads issued 1-2 iterations earlier -> waves keep 4-8 loads in flight, never
// drain vmcnt to 0 before compute.
__global__ __launch_bounds__(256) void k7_softmax(const float4* __restrict__ gu,
                                                  const float4* __restrict__ elog,
                                                  float4* __restrict__ out) {
    int wave = threadIdx.x >> 6;
    int lane = threadIdx.x & 63;
    int slot = blockIdx.x * 4 + wave;
    bool has1 = lane < 61;
    int i0 = lane, i1 = 64 + lane;

    int row0 = slot;
    int row1 = slot + RSTRIDE_;
    int row2 = slot + 2 * RSTRIDE_;
    if (row0 >= NROWS_) return;

    // prologue: g for row0,row1; e for row0
    const float4* pg0 = gu + (size_t)row0 * 125;
    float4 ga0 = pg0[i0];
    float4 ga1 = has1 ? pg0[i1] : ga0;
    int c1 = row1 < NROWS_ ? row1 : 0;
    const float4* pg1 = gu + (size_t)c1 * 125;
    float4 gb0 = pg1[i0];
    float4 gb1 = has1 ? pg1[i1] : gb0;
    const float4* pe0 = elog + (row0 % R_) * 125;
    float4 ea0 = pe0[i0];
    float4 ea1 = has1 ? pe0[i1] : ea0;

    while (row0 < NROWS_) {
        // issue prefetches FIRST: g depth-2, e depth-1
        int c2 = row2 < NROWS_ ? row2 : 0;
        const float4* pg2 = gu + (size_t)c2 * 125;
        float4 gc0 = pg2[i0];
        float4 gc1 = has1 ? pg2[i1] : gc0;
        int er1 = (row1 < NROWS_ ? row1 : 0) % R_;
        const float4* pe1 = elog + er1 * 125;
        float4 eb0 = pe1[i0];
        float4 eb1 = has1 ? pe1[i1] : eb0;

        // compute current row from (ga*, ea*) — loaded 1-2 iterations ago
        float p[8];
        p[0] = ea0.x * __builtin_amdgcn_rcpf(-__log2f(ga0.x));
        p[1] = ea0.y * __builtin_amdgcn_rcpf(-__log2f(ga0.y));
        p[2] = ea0.z * __builtin_amdgcn_rcpf(-__log2f(ga0.z));
        p[3] = ea0.w * __builtin_amdgcn_rcpf(-__log2f(ga0.w));
        if (has1) {
            p[4] = ea1.x * __builtin_amdgcn_rcpf(-__log2f(ga1.x));
            p[5] = ea1.y * __builtin_amdgcn_rcpf(-__log2f(ga1.y));
            p[6] = ea1.z * __builtin_amdgcn_rcpf(-__log2f(ga1.z));
            p[7] = ea1.w * __builtin_amdgcn_rcpf(-__log2f(ga1.w));
        } else {
            p[4] = p[5] = p[6] = p[7] = 0.f;
        }
        float s = ((p[0] + p[1]) + (p[2] + p[3])) + ((p[4] + p[5]) + (p[6] + p[7]));
#pragma unroll
        for (int off = 32; off > 0; off >>= 1) s += __shfl_xor(s, off);
        float inv = __builtin_amdgcn_rcpf(s);

        float4* orow = out + (size_t)row0 * 125;
        float4 o0 = {p[0] * inv, p[1] * inv, p[2] * inv, p[3] * inv};
        orow[i0] = o0;
        if (has1) {
            float4 o1 = {p[4] * inv, p[5] * inv, p[6] * inv, p[7] * inv};
            orow[i1] = o1;
        }

        // rotate registers / rows (all static names -> stays in VGPRs)
        ga0 = gb0; ga1 = gb1;
        gb0 = gc0; gb1 = gc1;
        ea0 = eb0; ea1 = eb1;
        row0 = row1; row1 = row2; row2 += RSTRIDE_;
    }
}

extern "C" void kernel_launch(void* const* d_in, const int* in_sizes, int n_in,
                              void* d_out, int out_size, void* d_ws, size_t ws_size,
                              hipStream_t stream) {
    const float* state  = (const float*)d_in[0];
    const float* dloc   = (const float*)d_in[1];
    const float* noise  = (const float*)d_in[2];
    const float* gu     = (const float*)d_in[3];
    const float* payoff = (const float*)d_in[4];
    const float* adj    = (const float*)d_in[5];
    const float* g1w    = (const float*)d_in[6];
    const float* g1b    = (const float*)d_in[7];
    const float* g2w    = (const float*)d_in[8];
    const float* g2b    = (const float*)d_in[9];
    const float* gamma  = (const float*)d_in[10];
    const float* beta   = (const float*)d_in[11];
    const float* aw     = (const float*)d_in[12];
    const float* av     = (const float*)d_in[13];
    float* out = (float*)d_out;

    float* ws     = (float*)d_ws;
    float* y1     = ws;           // 16000
    float* y2     = ws + 16000;   // 8000
    float* part1  = ws + 24000;   // 500*500 = 250000
    float* part2  = ws + 274000;  // 4*25000 = 100000
    float* elog   = ws + 374000;  // 25000   (total 399000 floats = 1.6 MB)

    k1_xw<<<T_, 256, 0, stream>>>(state, payoff, noise, g1w, y1);
    k2_adj_fused<<<T_, 256, 0, stream>>>(adj, y1, g1b, gamma, beta, g2w, y2);
    k3_adj2_aw<<<T_, 256, 0, stream>>>(adj, y2, g2b, gamma, beta, aw, part1);
    k4_logits_part<<<dim3(R_, 8), 256, 0, stream>>>(dloc, av, part1, part2);
    k4_reduce_exp<<<(R_ * T_ + 255) / 256, 256, 0, stream>>>(part2, elog);
    k7_softmax<<<RSTRIDE_ / 4, 256, 0, stream>>>(
        (const float4*)gu, (const float4*)elog, (float4*)out);
}